// Round 1
// baseline (113.173 us; speedup 1.0000x reference)
//
#include <hip/hip_runtime.h>

// YOLO loss on MI355X — round 8: break the FALSE roofline.
// Previous session computed "192 MB irreducible" — actual input is 96.3 MB
// (2 x 2048x196x30 fp32). The R4/R7 cell kernel ran at 3.7 TB/s (26 us),
// only 56% of the 6.55 TB/s this chip's own poison-fill sustains. New
// structure: persistent 1280-block grid (5 blocks/CU, LDS-capped residency),
// async global->LDS DMA staging (global_load_lds width=16: no VGPR
// round-trip, so the R5/R6 register-spill trap cannot recur), and a
// double-buffered ping-pong with counted s_waitcnt vmcnt(15) so one tile's
// 15,360 B is always in flight behind the previous tile's compute.
// bufA/bufB are distinct __shared__ objects + hand-unrolled alternation so
// the waitcnt-insertion pass can track LDS-DMA aliasing per buffer instead
// of conservatively draining vmcnt(0) at each ds_read.
// gfx9 s_waitcnt simm16: [3:0]=vm_lo [6:4]=exp [11:8]=lgkm [15:14]=vm_hi.
//   0x0F7F = vmcnt<=15 (other counters no-wait)  -> previous tile landed
//   0x0F70 = vmcnt==0                            -> drain (epilogue only)
//   0xC07F = lgkmcnt==0                          -> ds ops retired (WAR guard)

#define TILE 64
#define NBLK 1280   // 5 blocks/CU x 256 CU; 30,720 B LDS/block -> 5 resident

__device__ __forceinline__ void cp16(const void* g, void* l) {
    __builtin_amdgcn_global_load_lds(
        (const __attribute__((address_space(1))) void*)g,
        (__attribute__((address_space(3))) void*)l, 16, 0, 0);
}

// Stage one 64-cell tile (fused pred|targ image, 15,360 B) into buf.
// LDS dest is wave-uniform base + lane*16 (linear layout matches exactly);
// global source is per-lane, so the pred/targ boundary select is legal.
__device__ __forceinline__ void stage_tile(float4* __restrict__ buf,
                                           const float4* __restrict__ gp,
                                           const float4* __restrict__ gt,
                                           int lane) {
#pragma unroll
    for (int i = 0; i < 15; ++i) {
        int k = i * 64 + lane;                 // 0..959: <480 pred, else targ
        const float4* src = (k < 480) ? (gp + k) : (gt + (k - 480));
        cp16((const void*)src, (void*)(buf + i * 64));
    }
}

// Per-cell loss — arithmetic identical to the verified R4/R7 kernel.
__device__ __forceinline__ float cell_loss(const float* __restrict__ pv,
                                           const float* __restrict__ tv) {
    float conf_t = tv[4];
    if (conf_t == 0.0f) {
        float d4 = pv[4] - tv[4];
        float d9 = pv[9] - tv[9];
        return 0.5f * (d4 * d4 + d9 * d9);
    }
    float cls = 0.0f;
#pragma unroll
    for (int c = 10; c < 30; ++c) {
        float d = pv[c] - tv[c];
        cls += d * d;
    }

    float t0x = tv[0] / 14.0f, t0y = tv[1] / 14.0f;
    float tx1 = t0x - 0.5f * tv[2], ty1 = t0y - 0.5f * tv[3];
    float tx2 = t0x + 0.5f * tv[2], ty2 = t0y + 0.5f * tv[3];
    float area_t = (tx2 - tx1) * (ty2 - ty1);

    float iou0, iou1;
#pragma unroll
    for (int b = 0; b < 2; ++b) {
        float bx = pv[5*b + 0] / 14.0f, by = pv[5*b + 1] / 14.0f;
        float px1 = bx - 0.5f * pv[5*b + 2], py1 = by - 0.5f * pv[5*b + 3];
        float px2 = bx + 0.5f * pv[5*b + 2], py2 = by + 0.5f * pv[5*b + 3];
        float ltx = fmaxf(px1, tx1), lty = fmaxf(py1, ty1);
        float rbx = fminf(px2, tx2), rby = fminf(py2, ty2);
        float iw = fmaxf(rbx - ltx, 0.0f), ih = fmaxf(rby - lty, 0.0f);
        float inter = iw * ih;
        float area_p = (px2 - px1) * (py2 - py1);
        float v = inter / (area_p + area_t - inter);
        if (b == 0) iou0 = v; else iou1 = v;
    }

    bool sel1 = iou1 > iou0;              // tie -> box 0 (argmax semantics)
    float max_iou = sel1 ? iou1 : iou0;

    float ps0 = sel1 ? pv[5] : pv[0];
    float ps1 = sel1 ? pv[6] : pv[1];
    float ps2 = sel1 ? pv[7] : pv[2];
    float ps3 = sel1 ? pv[8] : pv[3];
    float ps4 = sel1 ? pv[9] : pv[4];
    float ts0 = sel1 ? tv[5] : tv[0];
    float ts1 = sel1 ? tv[6] : tv[1];
    float ts2 = sel1 ? tv[7] : tv[2];
    float ts3 = sel1 ? tv[8] : tv[3];
    float notresp_conf = sel1 ? pv[4] : pv[9];

    float dconf = ps4 - max_iou;
    float dx = ps0 - ts0, dy = ps1 - ts1;
    float dw = sqrtf(ps2) - sqrtf(ts2);
    float dh = sqrtf(ps3) - sqrtf(ts3);
    float loc = dx * dx + dy * dy + dw * dw + dh * dh;

    return 5.0f * loc + 2.0f * dconf * dconf
         + notresp_conf * notresp_conf + cls;
}

__device__ __forceinline__ float compute_tile(const float4* __restrict__ buf4,
                                              int lane) {
    const float* base = reinterpret_cast<const float*>(buf4);
    return cell_loss(base + lane * 30, base + TILE * 30 + lane * 30);
}

__global__ __launch_bounds__(64) void yolo_cell_kernel(
    const float* __restrict__ pred, const float* __restrict__ targ,
    float* __restrict__ block_sums, int n_cells)
{
    __shared__ float4 bufA[960];   // 15,360 B
    __shared__ float4 bufB[960];   // 15,360 B  (30,720 total -> 5 blocks/CU)
    const int lane = threadIdx.x;  // 0..63, one wave
    const int nt_full = n_cells >> 6;
    const float4* pred4 = reinterpret_cast<const float4*>(pred);
    const float4* targ4 = reinterpret_cast<const float4*>(targ);

    float acc = 0.0f;

    int t0 = (int)blockIdx.x;
    if (t0 < nt_full) {
        stage_tile(bufA, pred4 + (size_t)t0 * 480, targ4 + (size_t)t0 * 480, lane);
        int t1 = t0 + NBLK;
        for (;;) {
            if (t1 < nt_full) {
                __builtin_amdgcn_s_waitcnt(0xC07F);  // bufB ds-reads retired (WAR)
                stage_tile(bufB, pred4 + (size_t)t1 * 480, targ4 + (size_t)t1 * 480, lane);
                __builtin_amdgcn_s_waitcnt(0x0F7F);  // <=15 outstanding: bufA landed
                acc += compute_tile(bufA, lane);
                int t2 = t1 + NBLK;
                if (t2 < nt_full) {
                    __builtin_amdgcn_s_waitcnt(0xC07F);  // bufA ds-reads retired
                    stage_tile(bufA, pred4 + (size_t)t2 * 480, targ4 + (size_t)t2 * 480, lane);
                    __builtin_amdgcn_s_waitcnt(0x0F7F);  // bufB landed
                    acc += compute_tile(bufB, lane);
                    t0 = t2; t1 = t2 + NBLK;
                } else {
                    __builtin_amdgcn_s_waitcnt(0x0F70);  // drain: bufB landed
                    acc += compute_tile(bufB, lane);
                    break;
                }
            } else {
                __builtin_amdgcn_s_waitcnt(0x0F70);      // drain: bufA landed
                acc += compute_tile(bufA, lane);
                break;
            }
        }
    }

    // Tail partial tile (n_cells % 64 != 0 — not taken for B=2048): one
    // owner block, scalar staging. All pipeline exits drained vmcnt to 0,
    // and per-wave DS ops are in-order, so reusing bufA here is safe.
    int rem = n_cells & 63;
    if (rem && (int)blockIdx.x == (nt_full % NBLK)) {
        int cell0 = nt_full << 6;
        float* lds = reinterpret_cast<float*>(bufA);
        const float* gp = pred + (size_t)cell0 * 30;
        const float* gt = targ + (size_t)cell0 * 30;
        int nf = rem * 30;
        for (int i = lane; i < nf; i += 64) {
            lds[i] = gp[i];
            lds[TILE * 30 + i] = gt[i];
        }
        __builtin_amdgcn_s_waitcnt(0xC07F);
        if (lane < rem)
            acc += cell_loss(lds + lane * 30, lds + TILE * 30 + lane * 30);
    }

    // wave (64-lane) shuffle reduction; lane 0 writes the block partial
#pragma unroll
    for (int off = 32; off > 0; off >>= 1)
        acc += __shfl_down(acc, off, 64);
    if (lane == 0)
        block_sums[blockIdx.x] = acc;
}

__global__ __launch_bounds__(1024) void yolo_reduce_kernel(
    const float* __restrict__ block_sums, int n, double inv_batch,
    float* __restrict__ out)
{
    double acc = 0.0;
    for (int i = threadIdx.x; i < n; i += 1024)
        acc += (double)block_sums[i];
#pragma unroll
    for (int off = 32; off > 0; off >>= 1)
        acc += __shfl_down(acc, off, 64);

    __shared__ double wsum[16];
    int lane = threadIdx.x & 63;
    int wid  = threadIdx.x >> 6;
    if (lane == 0) wsum[wid] = acc;
    __syncthreads();
    if (threadIdx.x == 0) {
        double s = 0.0;
#pragma unroll
        for (int w = 0; w < 16; ++w) s += wsum[w];
        out[0] = (float)(s * inv_batch);
    }
}

extern "C" void kernel_launch(void* const* d_in, const int* in_sizes, int n_in,
                              void* d_out, int out_size, void* d_ws, size_t ws_size,
                              hipStream_t stream) {
    const float* pred = (const float*)d_in[0];
    const float* targ = (const float*)d_in[1];
    float* out = (float*)d_out;
    float* block_sums = (float*)d_ws;  // NBLK floats, fully written before read

    int n_elems = in_sizes[0];          // B*14*14*30
    int n_cells = n_elems / 30;         // B*196
    int n_batch = n_cells / (14 * 14);  // B

    yolo_cell_kernel<<<NBLK, TILE, 0, stream>>>(pred, targ, block_sums, n_cells);
    yolo_reduce_kernel<<<1, 1024, 0, stream>>>(block_sums, NBLK,
                                               1.0 / (double)n_batch, out);
}